// Round 6
// baseline (331.648 us; speedup 1.0000x reference)
//
#include <hip/hip_runtime.h>
#include <hip/hip_bf16.h>

#define BN 8
#define SS 1024
#define CC 512
#define HH 8
#define DD 64
#define PP 16
#define KT 1040
#define KTE 1088   // E head-row stride, padded to 64B multiple

typedef __hip_bfloat16 bf16;
typedef unsigned char uchar;
typedef unsigned short ushort;
typedef unsigned int uint;
typedef __attribute__((ext_vector_type(8))) short short8;
typedef __attribute__((ext_vector_type(4))) float f32x4;
typedef __attribute__((ext_vector_type(2))) float f32x2;

__device__ __forceinline__ short f2s(float v){ bf16 b = __float2bfloat16(v); return *(short*)&b; }
__device__ __forceinline__ float s2f(short s){ bf16 b; *(short*)&b = s; return __bfloat162float(b); }
__device__ __forceinline__ uchar f2q(float v){          // f32 -> fp8 e4m3 byte
    return (uchar)__builtin_amdgcn_cvt_pk_fp8_f32(v, v, 0, false);
}
__device__ __forceinline__ float rfl(float x){          // force to SGPR
    return __int_as_float(__builtin_amdgcn_readfirstlane(__float_as_int(x)));
}

#define MFMA16(a,b,c)  __builtin_amdgcn_mfma_f32_16x16x32_bf16(a,b,c,0,0,0)
#define MFMAF8(a,b,c)  __builtin_amdgcn_mfma_f32_16x16x32_fp8_fp8(a,b,c,0,0,0)

// ---------------------------------------------------------------------------
// P0: weight pre-conversion + persistent-token tails.
// ---------------------------------------------------------------------------
__global__ __launch_bounds__(256) void prep_kernel(
    const float* __restrict__ fc_w, const float* __restrict__ c1w,
    const float* __restrict__ c2w, const float* __restrict__ Wq,
    const float* __restrict__ Wk, const float* __restrict__ Wv,
    const float* __restrict__ th_post,
    const float* __restrict__ pk, const float* __restrict__ pv,
    short* __restrict__ Bfc, uchar* __restrict__ Bc1,
    uchar* __restrict__ Bc2, short* __restrict__ Bqkv,
    uchar* __restrict__ kf, uchar* __restrict__ vt)
{
    int i = blockIdx.x*256 + threadIdx.x;
    const int NFC = 512*512, NCV = 512*1536, NQ = 3*64*64, NP = BN*HH*PP*DD;
    if (i < NFC) {
        int c = i >> 9, r = i & 511;
        int g = r >> 6, d = r & 63;
        float s = 0.f;
        #pragma unroll
        for (int h = 0; h < 8; ++h)
            s += fc_w[(size_t)c*512 + h*64 + d] * th_post[h*8 + g];
        Bfc[i] = f2s(s);
        return;
    }
    i -= NFC;
    if (i < NCV) {
        int o = i/1536, r = i%1536, dk = r>>9, ci = r&511;
        Bc1[i] = f2q(c1w[(o*512+ci)*3+dk] * 16.f); return;
    }
    i -= NCV;
    if (i < NCV) {
        int o = i/1536, r = i%1536, dk = r>>9, ci = r&511;
        Bc2[i] = f2q(c2w[(o*512+ci)*3+dk] * 16.f); return;
    }
    i -= NCV;
    if (i < NQ) {
        int w = i >> 12, rest = i & 4095;
        const float* W = (w==0)?Wq:(w==1)?Wk:Wv;
        Bqkv[i] = f2s(W[((rest>>6)&63)*64 + (rest&63)]);
        return;
    }
    i -= NQ;
    if (i < NP) {
        int d = i & 63, p = (i >> 6) & 15, h = (i >> 10) & 7, n = i >> 13;
        size_t src = ((size_t)p*HH + h)*DD + d;
        kf[(((size_t)(n*HH+h))*KT + SS + p)*DD + d] = f2q(pk[src]);
        vt[(((size_t)(n*HH+h))*DD + d)*KT + SS + p] = f2q(pv[src]);
    }
}

// ---------------------------------------------------------------------------
// K1 v2: QKV projection, bf16 MFMA, XCD-swizzled.
// q/k out fp8 [s][d]; V -> transposed fp8 vt[nh][d][k=s].
// ---------------------------------------------------------------------------
__global__ __launch_bounds__(256) void qkv_mfma(
    const float* __restrict__ x, const short* __restrict__ Bqkv,
    uchar* __restrict__ qf, uchar* __restrict__ kf, uchar* __restrict__ vt)
{
    __shared__ short Xs[64*72];
    __shared__ short Ws[192*72];
    const int tid = threadIdx.x;
    const int lin = blockIdx.x;                     // grid 1024 linear
    const int xcd = lin & 7, slot = lin >> 3;       // slot in [0,128)
    const int m0 = (xcd*16 + (slot & 15))*64;
    const int h = slot >> 4;
    const int wave = tid >> 6, lane = tid & 63;
    const int lr = lane & 15, lq = lane >> 4;

    for (int i = tid; i < 1024; i += 256) {
        int r = i >> 4, cg = (i & 15)*4;
        float4 v = *(const float4*)(x + (size_t)(m0+r)*CC + h*64 + cg);
        Xs[r*72+cg+0] = f2s(v.x); Xs[r*72+cg+1] = f2s(v.y);
        Xs[r*72+cg+2] = f2s(v.z); Xs[r*72+cg+3] = f2s(v.w);
    }
    for (int i = tid; i < 3072; i += 256) {
        int r = i >> 4, cg = (i & 15)*4;
        *(short4*)(Ws + r*72 + cg) = *(const short4*)(Bqkv + (size_t)r*64 + cg);
    }
    __syncthreads();

    f32x4 acc[12];
    #pragma unroll
    for (int nt = 0; nt < 12; ++nt) acc[nt] = {0.f,0.f,0.f,0.f};
    #pragma unroll
    for (int ks = 0; ks < 2; ++ks) {
        int ko = ks*32 + lq*8;
        short8 a = *(const short8*)(Xs + (wave*16 + lr)*72 + ko);
        #pragma unroll
        for (int nt = 0; nt < 12; ++nt) {
            short8 b = *(const short8*)(Ws + (nt*16 + lr)*72 + ko);
            acc[nt] = MFMA16(a, b, acc[nt]);
        }
    }
    #pragma unroll
    for (int nt = 0; nt < 12; ++nt) {
        int ep = nt*16 + lr;
        int w = ep >> 6, e = ep & 63;
        #pragma unroll
        for (int reg = 0; reg < 4; ++reg) {
            int m = m0 + wave*16 + lq*4 + reg;
            int n = m >> 10, s = m & 1023;
            float v = acc[nt][reg];
            if (w == 0)      qf[((size_t)(n*HH+h)*SS + s)*DD + e] = f2q(v);
            else if (w == 1) kf[((size_t)(n*HH+h)*KT + s)*DD + e] = f2q(v);
            else             vt[(((size_t)(n*HH+h))*DD + e)*KT + s] = f2q(v);
        }
    }
}

// ---------------------------------------------------------------------------
// K2 v3: energy (RAW, pre-mix), fp8 MFMA NT, XCD-swizzled.
// E layout: [n][q][h][KTE] with KTE=1088 (64B-aligned head rows).
// ---------------------------------------------------------------------------
__device__ __forceinline__ void en_loadK(const uchar* __restrict__ kf,
    int nh, int kt, int tid, uint2* rk)
{
    #pragma unroll
    for (int j = 0; j < 2; ++j) {
        int i = tid + j*256;
        int r = i >> 3, c8 = (i & 7)*8;
        int kcol = kt*64 + r;
        uint2 v = {0u, 0u};
        if (kcol < KT)
            v = *(const uint2*)(kf + ((size_t)nh*KT + kcol)*DD + c8);
        rk[j] = v;
    }
}

__global__ __launch_bounds__(256) void energy_mfma8(
    const uchar* __restrict__ qf, const uchar* __restrict__ kf,
    uchar* __restrict__ E)
{
    __shared__ uchar Qs[64*72];
    __shared__ uchar Ks[64*72];
    const int tid = threadIdx.x;
    const int lin = blockIdx.x + 16*blockIdx.y;     // grid (16, 64)
    const int xcd = lin & 7, slot = lin >> 3;       // slot in [0,128)
    const int nh = xcd*8 + (slot & 7);
    const int mt = slot >> 3;
    const int wave = tid >> 6, lane = tid & 63;
    const int lr = lane & 15, lq = lane >> 4;
    const int n = nh >> 3, h = nh & 7;

    #pragma unroll
    for (int j = 0; j < 2; ++j) {
        int i = tid + j*256;
        int r = i >> 3, c8 = (i & 7)*8;
        *(uint2*)(Qs + r*72 + c8) =
            *(const uint2*)(qf + ((size_t)nh*SS + mt*64 + r)*DD + c8);
    }

    uint2 rk[2];
    en_loadK(kf, nh, 0, tid, rk);

    for (int kt = 0; kt < 17; ++kt) {
        if (kt) __syncthreads();
        #pragma unroll
        for (int j = 0; j < 2; ++j) {
            int i = tid + j*256;
            *(uint2*)(Ks + (i >> 3)*72 + (i & 7)*8) = rk[j];
        }
        __syncthreads();
        if (kt + 1 < 17) en_loadK(kf, nh, kt+1, tid, rk);

        f32x4 acc[4];
        #pragma unroll
        for (int nt = 0; nt < 4; ++nt) acc[nt] = {0.f,0.f,0.f,0.f};
        #pragma unroll
        for (int ks = 0; ks < 2; ++ks) {
            int ko = ks*32 + lq*8;
            long a = *(const long*)(Qs + (wave*16 + lr)*72 + ko);
            #pragma unroll
            for (int nt = 0; nt < 4; ++nt) {
                long b = *(const long*)(Ks + (nt*16 + lr)*72 + ko);
                acc[nt] = MFMAF8(a, b, acc[nt]);
            }
        }
        #pragma unroll
        for (int nt = 0; nt < 4; ++nt) {
            int kcol = kt*64 + nt*16 + lr;
            if (kcol >= KT) continue;
            #pragma unroll
            for (int reg = 0; reg < 4; ++reg) {
                int q = mt*64 + wave*16 + lq*4 + reg;
                E[(((size_t)(n*SS + q))*HH + h)*KTE + kcol] = f2q(acc[nt][reg]);
            }
        }
    }
}

// ---------------------------------------------------------------------------
// K3+K4 fused: pv_fused v5 — wave == ONE head; 512-thread blocks (8 waves).
// History: v2 spilled (thp SGPR overflow), v3 fixed spill but latency-bound
// at 2 waves/SIMD (VALUBusy 36%), v4's reg-prefetch re-spilled (128-VGPR
// hard cap). v5 keeps v3's inline loads but doubles TLP: 1 head per wave,
// 8 waves/block -> 16 waves/CU = 4 waves/SIMD. Live set ~105 VGPR < 128
// (acc 16, V-ops 16, rE 32 transient). E/mask reads 2x wave-redundant but
// L1-served (~12 KB unique per block-tile). Barrier-free as v3.
// Grid dim3(8,64): blockIdx.x = n == XCD -> vt L2-resident.
// ---------------------------------------------------------------------------
__global__ __launch_bounds__(512, 4) void pv_fused(
    const uchar* __restrict__ E, const uchar* __restrict__ vt,
    const int* __restrict__ mask, const float* __restrict__ th_pre,
    short* __restrict__ AO)
{
    __shared__ uchar Ps[8*16*72];        //  9 KB: p fp8, [h][q16][72]; per-wave slice
    __shared__ float Sred[16][8];        // 1/rowsum per (q,h); per-wave columns
    const int tid  = threadIdx.x;
    const int n    = blockIdx.x;         // 8  (== XCD)
    const int ql0  = blockIdx.y * 16;    // 64 q-tiles
    const int h    = tid >> 6;           // wave == head
    const int lane = tid & 63;
    const int lr = lane & 15, lq = lane >> 4;   // MFMA decomposition
    const int q_l = lane >> 2, kc = lane & 3;   // premix decomposition
    const int q  = ql0 + q_l;
    const int kcol0 = kc*16;             // this thread's 16-k group in a tile

    // this head's talking-heads weights (8 SGPRs) + mixed slope
    const float sc = 0.044194173824159216f * 1.4426950408889634f; // 1/sqrt(C)*log2e
    float tw[8], slmix, shf;
    {
        const float slv[8] = {0.5f,0.25f,0.125f,0.0625f,
                              0.03125f,0.015625f,0.0078125f,0.00390625f};
        const float maxd = (float)((q > SS-1-q) ? q : (SS-1-q));
        float sm = 0.f;
        #pragma unroll
        for (int g = 0; g < 8; ++g) {
            float v = rfl(th_pre[h*8+g] * sc);
            tw[g] = v;
            sm += v * slv[g];
        }
        slmix = rfl(sm);
        shf = fmaxf(0.f, -slmix * maxd);          // per-thread (q) VGPR
    }

    const uchar* Eb  = E  + ((size_t)(n*SS + q))*HH*KTE;  // head-0 row, this q
    const uchar* Vh  = vt + ((size_t)(n*HH) + h)*DD*KT;
    const int*  mrow = mask + (size_t)n*SS*SS + (size_t)q*SS;
    uchar* Psh = Ps + h*1152;

    float sums = 0.f;
    f32x4 acc[4];
    #pragma unroll
    for (int j = 0; j < 4; ++j) acc[j] = {0.f,0.f,0.f,0.f};

    for (int kt = 0; kt < 17; ++kt) {
        const int kb = kt*64;
        const bool body = (kt < 16);

        // ---- V operands for this head (L2-resident; issue first)
        long bva[2][4];
        #pragma unroll
        for (int ks = 0; ks < 2; ++ks)
            #pragma unroll
            for (int nt = 0; nt < 4; ++nt)
                bva[ks][nt] = *(const long*)(Vh + (size_t)(nt*16+lr)*KT + kb + ks*32 + lq*8);

        // ---- E tile: 8 g-rows x 16 k (uint4 each); mask 16 ints
        uint4 rE[8];
        #pragma unroll
        for (int g = 0; g < 8; ++g)
            rE[g] = *(const uint4*)(Eb + (size_t)g*KTE + kb + kcol0);
        int4 rm[4];
        if (body) {
            #pragma unroll
            for (int j = 0; j < 4; ++j)
                rm[j] = *(const int4*)(mrow + kb + kcol0 + j*4);
        }

        // ---- premix 1 head: 16 k per thread, 2 subpasses of 8
        #pragma unroll
        for (int s = 0; s < 2; ++s) {
            const int k0 = kb + kcol0 + s*8;         // global k of 8-col group
            const bool valid = (k0 < KT);            // tail: only kc==0 survives
            f32x4 tA, tB;
            if (body) {
                const float qv = (float)q, kf0 = (float)k0;
                f32x4 dA, dB;
                dA.x = fabsf(qv-kf0);      dA.y = fabsf(qv-kf0-1.f);
                dA.z = fabsf(qv-kf0-2.f);  dA.w = fabsf(qv-kf0-3.f);
                dB.x = fabsf(qv-kf0-4.f);  dB.y = fabsf(qv-kf0-5.f);
                dB.z = fabsf(qv-kf0-6.f);  dB.w = fabsf(qv-kf0-7.f);
                tA = -dA*slmix - shf;
                tB = -dB*slmix - shf;
            } else {
                tA = {-shf,-shf,-shf,-shf};
                tB = tA;
            }
            #pragma unroll
            for (int g = 0; g < 8; ++g) {
                const uint w0 = (s == 0) ? rE[g].x : rE[g].z;
                const uint w1 = (s == 0) ? rE[g].y : rE[g].w;
                f32x2 lo0 = __builtin_amdgcn_cvt_pk_f32_fp8((int)w0, false);
                f32x2 hi0 = __builtin_amdgcn_cvt_pk_f32_fp8((int)w0, true);
                f32x2 lo1 = __builtin_amdgcn_cvt_pk_f32_fp8((int)w1, false);
                f32x2 hi1 = __builtin_amdgcn_cvt_pk_f32_fp8((int)w1, true);
                f32x4 aA; aA.x=lo0.x; aA.y=lo0.y; aA.z=hi0.x; aA.w=hi0.y;
                f32x4 aB; aB.x=lo1.x; aB.y=lo1.y; aB.z=hi1.x; aB.w=hi1.y;
                tA += aA * tw[g];
                tB += aB * tw[g];
            }
            f32x4 eA, eB;
            if (body) {
                const int4 rmA = rm[2*s], rmB = rm[2*s+1];
                eA.x = (rmA.x==0)?0.f:exp2f(tA.x);
                eA.y = (rmA.y==0)?0.f:exp2f(tA.y);
                eA.z = (rmA.z==0)?0.f:exp2f(tA.z);
                eA.w = (rmA.w==0)?0.f:exp2f(tA.w);
                eB.x = (rmB.x==0)?0.f:exp2f(tB.x);
                eB.y = (rmB.y==0)?0.f:exp2f(tB.y);
                eB.z = (rmB.z==0)?0.f:exp2f(tB.z);
                eB.w = (rmB.w==0)?0.f:exp2f(tB.w);
            } else if (valid) {          // persistent keys: no bias, no mask
                eA.x = exp2f(tA.x); eA.y = exp2f(tA.y);
                eA.z = exp2f(tA.z); eA.w = exp2f(tA.w);
                eB.x = exp2f(tB.x); eB.y = exp2f(tB.y);
                eB.z = exp2f(tB.z); eB.w = exp2f(tB.w);
            } else {
                eA = {0.f,0.f,0.f,0.f}; eB = {0.f,0.f,0.f,0.f};
            }
            sums += (eA.x+eA.y)+(eA.z+eA.w) + (eB.x+eB.y)+(eB.z+eB.w);
            int p0 = __builtin_amdgcn_cvt_pk_fp8_f32(eA.x, eA.y, 0, false);
            p0 = __builtin_amdgcn_cvt_pk_fp8_f32(eA.z, eA.w, p0, true);
            int p1 = __builtin_amdgcn_cvt_pk_fp8_f32(eB.x, eB.y, 0, false);
            p1 = __builtin_amdgcn_cvt_pk_fp8_f32(eB.z, eB.w, p1, true);
            uint2 pw; pw.x = (uint)p0; pw.y = (uint)p1;
            *(uint2*)(Psh + q_l*72 + kcol0 + s*8) = pw;
        }

        // ---- MFMA (same-wave Ps ordering via compiler lgkmcnt; no barriers)
        #pragma unroll
        for (int ks = 0; ks < 2; ++ks) {
            int ko = ks*32 + lq*8;
            long av = *(const long*)(Psh + lr*72 + ko);
            #pragma unroll
            for (int nt = 0; nt < 4; ++nt)
                acc[nt] = MFMAF8(av, bva[ks][nt], acc[nt]);
        }
    }

    // ---- row sums: reduce over the 4 kc lanes of each q_l -> 1/sum in LDS
    {
        float s = sums;
        s += __shfl_xor(s, 1); s += __shfl_xor(s, 2);
        if (kc == 0) Sred[q_l][h] = 1.0f / s;
    }
    // (same-wave LDS write->read; compiler inserts lgkmcnt)

    // ---- normalize + store AO (bf16)
    #pragma unroll
    for (int reg = 0; reg < 4; ++reg) {
        float inv = Sred[lq*4 + reg][h];
        int qg = ql0 + lq*4 + reg;
        #pragma unroll
        for (int nt = 0; nt < 4; ++nt) {
            int d = nt*16 + lr;
            AO[((size_t)(n*SS) + qg)*CC + h*64 + d] = f2s(acc[nt][reg] * inv);
        }
    }
}

// ---------------------------------------------------------------------------
// K5: fc (th_post folded into weights), bf16 MFMA, 64x64, XCD-swizzled.
// ---------------------------------------------------------------------------
__device__ __forceinline__ void g_load4(const short* __restrict__ src,
    size_t rowstride, int row0, int col0, int tid, short4* r)
{
    #pragma unroll
    for (int j = 0; j < 4; ++j) {
        int i = tid + j*256;
        int rr = i >> 4, cg = (i & 15)*4;
        r[j] = *(const short4*)(src + (size_t)(row0 + rr)*rowstride + col0 + cg);
    }
}
__device__ __forceinline__ void lds_store4(short* __restrict__ dst,
    int tid, const short4* r)
{
    #pragma unroll
    for (int j = 0; j < 4; ++j) {
        int i = tid + j*256;
        *(short4*)(dst + (i >> 4)*72 + (i & 15)*4) = r[j];
    }
}

__global__ __launch_bounds__(256) void fc_mfma(
    const short* __restrict__ A, const short* __restrict__ Bt,
    const float* __restrict__ bias, const float* __restrict__ x,
    short* __restrict__ out, uchar* __restrict__ out8)
{
    __shared__ short As[64*72];
    __shared__ short Bs[64*72];
    const int tid = threadIdx.x;
    const int lin = blockIdx.x + 8*blockIdx.y;      // grid (8,128)
    const int xcd = lin & 7, slot = lin >> 3;
    const int m0 = (xcd*16 + (slot & 15))*64;
    const int n0 = (slot >> 4)*64;
    const int wave = tid >> 6, lane = tid & 63;
    const int lr = lane & 15, lq = lane >> 4;

    short4 ra[4], rb[4];
    g_load4(A, CC, m0, 0, tid, ra);
    g_load4(Bt, CC, n0, 0, tid, rb);

    f32x4 acc[4];
    #pragma unroll
    for (int nt = 0; nt < 4; ++nt) acc[nt] = {0.f,0.f,0.f,0.f};

    for (int kt = 0; kt < CC; kt += 64) {
        if (kt) __syncthreads();
        lds_store4(As, tid, ra);
        lds_store4(Bs, tid, rb);
        __syncthreads();
        if (kt + 64 < CC) {
            g_load4(A, CC, m0, kt+64, tid, ra);
            g_load4(Bt, CC, n0, kt+64, tid, rb);
        }
        #pragma unroll
        for (int ks = 0; ks < 2; ++ks) {
            int ko = ks*32 + lq*8;
            short8 a = *(const short8*)(As + (wave*16 + lr)*72 + ko);
            #pragma unroll
            for (int nt = 0; nt < 4; ++nt) {
                short8 b = *(const short8*)(Bs + (nt*16 + lr)*72 + ko);
                acc[nt] = MFMA16(a, b, acc[nt]);
            }
        }
    }
    #pragma unroll
    for (int nt = 0; nt < 4; ++nt) {
        int nn = n0 + nt*16 + lr;
        #pragma unroll
        for (int reg = 0; reg < 4; ++reg) {
            int m = m0 + wave*16 + lq*4 + reg;
            float v = acc[nt][reg] + bias[nn] + x[(size_t)m*CC + nn];
            out[(size_t)m*CC + nn]  = f2s(v);
            out8[(size_t)m*CC + nn] = f2q(v);
        }
    }
}

// ---------------------------------------------------------------------------
// K6 v2: causal conv fp8 NT GEMM, BK=128 (12 K-iters), XCD-swizzled.
// ---------------------------------------------------------------------------
__device__ __forceinline__ void conv_loadA8w(const uchar* __restrict__ A,
    int m0, int kt, int tid, uint2* ra)
{
    const int shift = (kt >> 9) - 2;
    const int ci0 = kt & 511;
    #pragma unroll
    for (int j = 0; j < 4; ++j) {
        int i = tid + j*256;
        int rr = i >> 4, c8 = (i & 15)*8;
        int m = m0 + rr;
        int s = m & (SS-1);
        uint2 v = {0u, 0u};
        if (s + shift >= 0)
            v = *(const uint2*)(A + (size_t)(m + shift)*CC + ci0 + c8);
        ra[j] = v;
    }
}
__device__ __forceinline__ void g_load8w(const uchar* __restrict__ src,
    size_t rowstride, int row0, int col0, int tid, uint2* r)
{
    #pragma unroll
    for (int j = 0; j < 4; ++j) {
        int i = tid + j*256;
        int rr = i >> 4, c8 = (i & 15)*8;
        r[j] = *(const uint2*)(src + (size_t)(row0 + rr)*rowstride + col0 + c8);
    }
}
__device__ __forceinline__ void lds_store8w(uchar* __restrict__ dst,
    int tid, const uint2* r)
{
    #pragma unroll
    for (int j = 0; j < 4; ++j) {
        int i = tid + j*256;
        *(uint2*)(dst + (i >> 4)*136 + (i & 15)*8) = r[j];
    }
}

__global__ __launch_bounds__(256) void conv_mfma8(
    const uchar* __restrict__ A, const uchar* __restrict__ Bt,
    const float* __restrict__ bias, uchar* __restrict__ out8,
    short* __restrict__ out16, int f8out)
{
    __shared__ uchar As[64*136];
    __shared__ uchar Bs[64*136];
    const int tid = threadIdx.x;
    const int lin = blockIdx.x + 8*blockIdx.y;      // grid (8,128)
    const int xcd = lin & 7, slot = lin >> 3;
    const int m0 = (xcd*16 + (slot & 15))*64;
    const int n0 = (slot >> 4)*64;
    const int wave = tid >> 6, lane = tid & 63;
    const int lr = lane & 15, lq = lane >> 4;

    uint2 ra[4], rb[4];
    conv_loadA8w(A, m0, 0, tid, ra);
    g_load8w(Bt, 1536, n0, 0, tid, rb);

    f32x4 acc[4];
    #pragma unroll
    for (int nt = 0; nt < 4; ++nt) acc[nt] = {0.f,0.f,0.f,0.f};

    for (int kt = 0; kt < 1536; kt += 128) {
        if (kt) __syncthreads();
        lds_store8w(As, tid, ra);
        lds_store8w(Bs, tid, rb);
        __syncthreads();
        if (kt + 128 < 1536) {
            conv_loadA8w(A, m0, kt+128, tid, ra);
            g_load8w(Bt, 1536, n0, kt+128, tid, rb);
        }
        #pragma unroll
        for (int ks = 0; ks < 4; ++ks) {
            int ko = ks*32 + lq*8;
            long a = *(const long*)(As + (wave*16 + lr)*136 + ko);
            #pragma unroll
            for (int nt = 0; nt < 4; ++nt) {
                long b = *(const long*)(Bs + (nt*16 + lr)*136 + ko);
                acc[nt] = MFMAF8(a, b, acc[nt]);
            }
        }
    }
    #pragma unroll
    for (int nt = 0; nt < 4; ++nt) {
        int nn = n0 + nt*16 + lr;
        #pragma unroll
        for (int reg = 0; reg < 4; ++reg) {
            int m = m0 + wave*16 + lq*4 + reg;
            float v = fmaxf(acc[nt][reg]*0.0625f + bias[nn], 0.f);
            if (f8out) out8[(size_t)m*CC + nn]  = f2q(v);
            else       out16[(size_t)m*CC + nn] = f2s(v);
        }
    }
}

// ---------------------------------------------------------------------------
// K7: out = LN(relu(c2 + xres) masked) * g + b.  4 rows per block.
// ---------------------------------------------------------------------------
__global__ __launch_bounds__(256) void final_kernel(
    const short* __restrict__ c2, const short* __restrict__ xres,
    const int* __restrict__ mask, const float* __restrict__ g,
    const float* __restrict__ b, float* __restrict__ out)
{
    __shared__ float red[256];
    const int tid = threadIdx.x;
    const int m0 = blockIdx.x * 4;
    const int c0 = tid*2;
    const float2 gg = *(const float2*)(g + c0);
    const float2 bb = *(const float2*)(b + c0);

    for (int rr = 0; rr < 4; ++rr) {
        const int m = m0 + rr;
        const int n = m >> 10, s = m & 1023;
        const int mk = mask[(size_t)n*SS*SS + (size_t)s*SS];

        short2 ca = *(const short2*)(c2 + (size_t)m*CC + c0);
        short2 xa = *(const short2*)(xres + (size_t)m*CC + c0);
        float v0 = fmaxf(s2f(ca.x) + s2f(xa.x), 0.f);
        float v1 = fmaxf(s2f(ca.y) + s2f(xa.y), 0.f);
        if (mk == 0) { v0 = 0.f; v1 = 0.f; }

        red[tid] = v0 + v1;
        __syncthreads();
        for (int off = 128; off > 0; off >>= 1) {
            if (tid < off) red[tid] += red[tid + off];
            __syncthreads();
        }
        float mu = red[0] * (1.0f/512.0f);
        __syncthreads();
        float d0 = v0 - mu, d1 = v1 - mu;
        red[tid] = d0*d0 + d1*d1;
        __syncthreads();
        for (int off = 128; off > 0; off >>= 1) {
            if (tid < off) red[tid] += red[tid + off];
            __syncthreads();
        }
        float rstd = rsqrtf(red[0] * (1.0f/512.0f) + 1e-5f);
        float2 o;
        o.x = d0*rstd*gg.x + bb.x;
        o.y = d1*rstd*gg.y + bb.y;
        *(float2*)(out + (size_t)m*CC + c0) = o;
        __syncthreads();                     // red reuse next row
    }
}

// ---------------------------------------------------------------------------
extern "C" void kernel_launch(void* const* d_in, const int* in_sizes, int n_in,
                              void* d_out, int out_size, void* d_ws, size_t ws_size,
                              hipStream_t stream)
{
    const float* x      = (const float*)d_in[0];
    const int*   mask   = (const int*)  d_in[1];
    const float* Wq     = (const float*)d_in[2];
    const float* Wk     = (const float*)d_in[3];
    const float* Wv     = (const float*)d_in[4];
    const float* pk     = (const float*)d_in[5];
    const float* pv     = (const float*)d_in[6];
    const float* th_pre = (const float*)d_in[7];
    const float* th_post= (const float*)d_in[8];
    const float* fc_w   = (const float*)d_in[9];
    const float* fc_b   = (const float*)d_in[10];
    const float* c1w    = (const float*)d_in[11];
    const float* c1b    = (const float*)d_in[12];
    const float* c2w    = (const float*)d_in[13];
    const float* c2b    = (const float*)d_in[14];
    const float* lng    = (const float*)d_in[15];
    const float* lnb    = (const float*)d_in[16];
    float* out = (float*)d_out;
    (void)in_sizes; (void)n_in; (void)out_size; (void)ws_size;

    char* ws = (char*)d_ws;
    const size_t SZ_Q  = (size_t)BN*HH*SS*DD;      //  4.19 MB (fp8)
    const size_t SZ_K  = (size_t)BN*HH*KT*DD;      //  4.26 MB (fp8)
    const size_t SZ_VT = (size_t)BN*HH*DD*KT;      //  4.26 MB (fp8)
    const size_t SZ_E  = (size_t)BN*SS*HH*KTE;     // 71.3 MB (fp8, raw energy)
    const size_t SZ_A  = (size_t)BN*SS*CC*2;       //  8.39 MB (bf16)
    const size_t SZ_A8 = (size_t)BN*SS*CC;         //  4.19 MB (fp8)

    uchar* qf  = (uchar*)(ws);
    uchar* kf  = (uchar*)(ws + SZ_Q);
    uchar* vt  = (uchar*)(ws + SZ_Q + SZ_K);
    uchar* E   = (uchar*)(ws + SZ_Q + SZ_K + SZ_VT);
    short* AO  = (short*)(ws + SZ_Q + SZ_K + SZ_VT + SZ_E);
    char*  wend = ws + SZ_Q + SZ_K + SZ_VT + SZ_E + SZ_A;
    short* Bfc = (short*)(wend);
    uchar* Bc1 = (uchar*)(wend + 512*512*2);
    uchar* Bc2 = (uchar*)(wend + 512*512*2 + 512*1536);
    short* Bqkv= (short*)(wend + 512*512*2 + 2*512*1536);
    uchar* xres8 = (uchar*)(wend + 512*512*2 + 2*512*1536 + 3*64*64*2);
    short* c2buf = (short*)(wend + 512*512*2 + 2*512*1536 + 3*64*64*2 + SZ_A8);
    // Aliases (dead regions): xres(bf16) over qf+kf (dead after energy);
    // h1(fp8) over E (dead after pv_fused).
    short* xres = (short*)(ws);
    uchar* h18  = (uchar*)E;
    // total ws ~= 106 MB (ws_size >= 256 MiB)

    {
        int total = 512*512 + 2*512*1536 + 3*64*64 + BN*HH*PP*DD;
        prep_kernel<<<(total + 255)/256, 256, 0, stream>>>(
            fc_w, c1w, c2w, Wq, Wk, Wv, th_post, pk, pv,
            Bfc, Bc1, Bc2, Bqkv, kf, vt);
    }
    qkv_mfma<<<BN*SS/64*HH, 256, 0, stream>>>(x, Bqkv, qf, kf, vt);

    energy_mfma8<<<dim3(16, 64), 256, 0, stream>>>(qf, kf, E);
    pv_fused<<<dim3(8, 64), 512, 0, stream>>>(E, vt, mask, th_pre, AO);

    fc_mfma<<<dim3(8, 128), 256, 0, stream>>>(AO, Bfc, fc_b, x, xres, xres8);
    conv_mfma8<<<dim3(8, 128), 256, 0, stream>>>(xres8, Bc1, c1b, h18, (short*)nullptr, 1);
    conv_mfma8<<<dim3(8, 128), 256, 0, stream>>>(h18, Bc2, c2b, (uchar*)nullptr, c2buf, 0);
    final_kernel<<<BN*SS/4, 256, 0, stream>>>(c2buf, xres, mask, lng, lnb, out);
}

// Round 7
// 299.291 us; speedup vs baseline: 1.1081x; 1.1081x over previous
//
#include <hip/hip_runtime.h>
#include <hip/hip_bf16.h>

#define BN 8
#define SS 1024
#define CC 512
#define HH 8
#define DD 64
#define PP 16
#define KT 1040
#define KTE 1088   // E head-row stride, padded to 64B multiple

typedef __hip_bfloat16 bf16;
typedef unsigned char uchar;
typedef unsigned short ushort;
typedef unsigned int uint;
typedef __attribute__((ext_vector_type(8))) short short8;
typedef __attribute__((ext_vector_type(4))) float f32x4;
typedef __attribute__((ext_vector_type(2))) float f32x2;

__device__ __forceinline__ short f2s(float v){ bf16 b = __float2bfloat16(v); return *(short*)&b; }
__device__ __forceinline__ float s2f(short s){ bf16 b; *(short*)&b = s; return __bfloat162float(b); }
__device__ __forceinline__ uchar f2q(float v){          // f32 -> fp8 e4m3 byte
    return (uchar)__builtin_amdgcn_cvt_pk_fp8_f32(v, v, 0, false);
}
__device__ __forceinline__ float rfl(float x){          // force to SGPR
    return __int_as_float(__builtin_amdgcn_readfirstlane(__float_as_int(x)));
}

#define MFMA16(a,b,c)  __builtin_amdgcn_mfma_f32_16x16x32_bf16(a,b,c,0,0,0)
#define MFMAF8(a,b,c)  __builtin_amdgcn_mfma_f32_16x16x32_fp8_fp8(a,b,c,0,0,0)

// ---------------------------------------------------------------------------
// P0: weight pre-conversion + persistent-token tails.
// ---------------------------------------------------------------------------
__global__ __launch_bounds__(256) void prep_kernel(
    const float* __restrict__ fc_w, const float* __restrict__ c1w,
    const float* __restrict__ c2w, const float* __restrict__ Wq,
    const float* __restrict__ Wk, const float* __restrict__ Wv,
    const float* __restrict__ th_post,
    const float* __restrict__ pk, const float* __restrict__ pv,
    short* __restrict__ Bfc, uchar* __restrict__ Bc1,
    uchar* __restrict__ Bc2, short* __restrict__ Bqkv,
    uchar* __restrict__ kf, uchar* __restrict__ vt)
{
    int i = blockIdx.x*256 + threadIdx.x;
    const int NFC = 512*512, NCV = 512*1536, NQ = 3*64*64, NP = BN*HH*PP*DD;
    if (i < NFC) {
        int c = i >> 9, r = i & 511;
        int g = r >> 6, d = r & 63;
        float s = 0.f;
        #pragma unroll
        for (int h = 0; h < 8; ++h)
            s += fc_w[(size_t)c*512 + h*64 + d] * th_post[h*8 + g];
        Bfc[i] = f2s(s);
        return;
    }
    i -= NFC;
    if (i < NCV) {
        int o = i/1536, r = i%1536, dk = r>>9, ci = r&511;
        Bc1[i] = f2q(c1w[(o*512+ci)*3+dk] * 16.f); return;
    }
    i -= NCV;
    if (i < NCV) {
        int o = i/1536, r = i%1536, dk = r>>9, ci = r&511;
        Bc2[i] = f2q(c2w[(o*512+ci)*3+dk] * 16.f); return;
    }
    i -= NCV;
    if (i < NQ) {
        int w = i >> 12, rest = i & 4095;
        const float* W = (w==0)?Wq:(w==1)?Wk:Wv;
        Bqkv[i] = f2s(W[((rest>>6)&63)*64 + (rest&63)]);
        return;
    }
    i -= NQ;
    if (i < NP) {
        int d = i & 63, p = (i >> 6) & 15, h = (i >> 10) & 7, n = i >> 13;
        size_t src = ((size_t)p*HH + h)*DD + d;
        kf[(((size_t)(n*HH+h))*KT + SS + p)*DD + d] = f2q(pk[src]);
        vt[(((size_t)(n*HH+h))*DD + d)*KT + SS + p] = f2q(pv[src]);
    }
}

// ---------------------------------------------------------------------------
// K1 v2: QKV projection, bf16 MFMA, XCD-swizzled.
// q/k out fp8 [s][d]; V -> transposed fp8 vt[nh][d][k=s].
// ---------------------------------------------------------------------------
__global__ __launch_bounds__(256) void qkv_mfma(
    const float* __restrict__ x, const short* __restrict__ Bqkv,
    uchar* __restrict__ qf, uchar* __restrict__ kf, uchar* __restrict__ vt)
{
    __shared__ short Xs[64*72];
    __shared__ short Ws[192*72];
    const int tid = threadIdx.x;
    const int lin = blockIdx.x;                     // grid 1024 linear
    const int xcd = lin & 7, slot = lin >> 3;       // slot in [0,128)
    const int m0 = (xcd*16 + (slot & 15))*64;
    const int h = slot >> 4;
    const int wave = tid >> 6, lane = tid & 63;
    const int lr = lane & 15, lq = lane >> 4;

    for (int i = tid; i < 1024; i += 256) {
        int r = i >> 4, cg = (i & 15)*4;
        float4 v = *(const float4*)(x + (size_t)(m0+r)*CC + h*64 + cg);
        Xs[r*72+cg+0] = f2s(v.x); Xs[r*72+cg+1] = f2s(v.y);
        Xs[r*72+cg+2] = f2s(v.z); Xs[r*72+cg+3] = f2s(v.w);
    }
    for (int i = tid; i < 3072; i += 256) {
        int r = i >> 4, cg = (i & 15)*4;
        *(short4*)(Ws + r*72 + cg) = *(const short4*)(Bqkv + (size_t)r*64 + cg);
    }
    __syncthreads();

    f32x4 acc[12];
    #pragma unroll
    for (int nt = 0; nt < 12; ++nt) acc[nt] = {0.f,0.f,0.f,0.f};
    #pragma unroll
    for (int ks = 0; ks < 2; ++ks) {
        int ko = ks*32 + lq*8;
        short8 a = *(const short8*)(Xs + (wave*16 + lr)*72 + ko);
        #pragma unroll
        for (int nt = 0; nt < 12; ++nt) {
            short8 b = *(const short8*)(Ws + (nt*16 + lr)*72 + ko);
            acc[nt] = MFMA16(a, b, acc[nt]);
        }
    }
    #pragma unroll
    for (int nt = 0; nt < 12; ++nt) {
        int ep = nt*16 + lr;
        int w = ep >> 6, e = ep & 63;
        #pragma unroll
        for (int reg = 0; reg < 4; ++reg) {
            int m = m0 + wave*16 + lq*4 + reg;
            int n = m >> 10, s = m & 1023;
            float v = acc[nt][reg];
            if (w == 0)      qf[((size_t)(n*HH+h)*SS + s)*DD + e] = f2q(v);
            else if (w == 1) kf[((size_t)(n*HH+h)*KT + s)*DD + e] = f2q(v);
            else             vt[(((size_t)(n*HH+h))*DD + e)*KT + s] = f2q(v);
        }
    }
}

// ---------------------------------------------------------------------------
// K2 v3: energy (RAW, pre-mix), fp8 MFMA NT, XCD-swizzled.
// E layout: [n][q][h][KTE] with KTE=1088 (64B-aligned head rows).
// ---------------------------------------------------------------------------
__device__ __forceinline__ void en_loadK(const uchar* __restrict__ kf,
    int nh, int kt, int tid, uint2* rk)
{
    #pragma unroll
    for (int j = 0; j < 2; ++j) {
        int i = tid + j*256;
        int r = i >> 3, c8 = (i & 7)*8;
        int kcol = kt*64 + r;
        uint2 v = {0u, 0u};
        if (kcol < KT)
            v = *(const uint2*)(kf + ((size_t)nh*KT + kcol)*DD + c8);
        rk[j] = v;
    }
}

__global__ __launch_bounds__(256) void energy_mfma8(
    const uchar* __restrict__ qf, const uchar* __restrict__ kf,
    uchar* __restrict__ E)
{
    __shared__ uchar Qs[64*72];
    __shared__ uchar Ks[64*72];
    const int tid = threadIdx.x;
    const int lin = blockIdx.x + 16*blockIdx.y;     // grid (16, 64)
    const int xcd = lin & 7, slot = lin >> 3;       // slot in [0,128)
    const int nh = xcd*8 + (slot & 7);
    const int mt = slot >> 3;
    const int wave = tid >> 6, lane = tid & 63;
    const int lr = lane & 15, lq = lane >> 4;
    const int n = nh >> 3, h = nh & 7;

    #pragma unroll
    for (int j = 0; j < 2; ++j) {
        int i = tid + j*256;
        int r = i >> 3, c8 = (i & 7)*8;
        *(uint2*)(Qs + r*72 + c8) =
            *(const uint2*)(qf + ((size_t)nh*SS + mt*64 + r)*DD + c8);
    }

    uint2 rk[2];
    en_loadK(kf, nh, 0, tid, rk);

    for (int kt = 0; kt < 17; ++kt) {
        if (kt) __syncthreads();
        #pragma unroll
        for (int j = 0; j < 2; ++j) {
            int i = tid + j*256;
            *(uint2*)(Ks + (i >> 3)*72 + (i & 7)*8) = rk[j];
        }
        __syncthreads();
        if (kt + 1 < 17) en_loadK(kf, nh, kt+1, tid, rk);

        f32x4 acc[4];
        #pragma unroll
        for (int nt = 0; nt < 4; ++nt) acc[nt] = {0.f,0.f,0.f,0.f};
        #pragma unroll
        for (int ks = 0; ks < 2; ++ks) {
            int ko = ks*32 + lq*8;
            long a = *(const long*)(Qs + (wave*16 + lr)*72 + ko);
            #pragma unroll
            for (int nt = 0; nt < 4; ++nt) {
                long b = *(const long*)(Ks + (nt*16 + lr)*72 + ko);
                acc[nt] = MFMAF8(a, b, acc[nt]);
            }
        }
        #pragma unroll
        for (int nt = 0; nt < 4; ++nt) {
            int kcol = kt*64 + nt*16 + lr;
            if (kcol >= KT) continue;
            #pragma unroll
            for (int reg = 0; reg < 4; ++reg) {
                int q = mt*64 + wave*16 + lq*4 + reg;
                E[(((size_t)(n*SS + q))*HH + h)*KTE + kcol] = f2q(acc[nt][reg]);
            }
        }
    }
}

// ---------------------------------------------------------------------------
// K3+K4 fused: pv_fused v6 — 1 head per wave, 256-thr blocks, grid (8,128).
// History: v3 (2 heads/wave, 2 blk/CU) = 97us latency-bound @2 waves/SIMD;
// v4 reg-prefetch spilled (>128 VGPR); v5 (512thr, lb(512,4)) made the
// allocator squeeze to the 64-VGPR tier and spill (WRITE 30MB, 127us).
// v6: v3's loose-bound compile regime (lb(256,2) -> natural ~100 VGPR, no
// spill) + v5's TLP decomposition via the GRID: 4 heads per block (1 per
// wave), q-tile x head-group grid (8,128) -> 4 blocks/CU = 4 waves/SIMD.
// Barrier-free (waves fully independent). LDS ~5 KB.
// blockIdx.x = n == XCD -> vt L2-resident.
// ---------------------------------------------------------------------------
__global__ __launch_bounds__(256, 2) void pv_fused(
    const uchar* __restrict__ E, const uchar* __restrict__ vt,
    const int* __restrict__ mask, const float* __restrict__ th_pre,
    short* __restrict__ AO)
{
    __shared__ uchar Ps[4*16*72];        // 4.5 KB: p fp8, [wave][q16][72]
    __shared__ float Sred[16][4];        // 1/rowsum per (q, wave)
    const int tid  = threadIdx.x;
    const int n    = blockIdx.x;         // 8  (== XCD)
    const int yy   = blockIdx.y;         // 128 = 64 q-tiles x 2 head-groups
    const int ql0  = (yy >> 1) * 16;
    const int hg   = (yy & 1) * 4;
    const int wave = tid >> 6, lane = tid & 63;
    const int h    = hg + wave;          // this wave's head
    const int lr = lane & 15, lq = lane >> 4;   // MFMA decomposition
    const int q_l = lane >> 2, kc = lane & 3;   // premix decomposition
    const int q  = ql0 + q_l;
    const int kcol0 = kc*16;             // this thread's 16-k group in a tile

    // this head's talking-heads weights (8 SGPRs) + mixed slope
    const float sc = 0.044194173824159216f * 1.4426950408889634f; // 1/sqrt(C)*log2e
    float tw[8], slmix, shf;
    {
        const float slv[8] = {0.5f,0.25f,0.125f,0.0625f,
                              0.03125f,0.015625f,0.0078125f,0.00390625f};
        const float maxd = (float)((q > SS-1-q) ? q : (SS-1-q));
        float sm = 0.f;
        #pragma unroll
        for (int g = 0; g < 8; ++g) {
            float v = rfl(th_pre[h*8+g] * sc);
            tw[g] = v;
            sm += v * slv[g];
        }
        slmix = rfl(sm);
        shf = fmaxf(0.f, -slmix * maxd);          // per-thread (q) VGPR
    }

    const uchar* Eb  = E  + ((size_t)(n*SS + q))*HH*KTE;  // head-0 row, this q
    const uchar* Vh  = vt + ((size_t)(n*HH) + h)*DD*KT;
    const int*  mrow = mask + (size_t)n*SS*SS + (size_t)q*SS;
    uchar* Psh = Ps + wave*1152;

    float sums = 0.f;
    f32x4 acc[4];
    #pragma unroll
    for (int j = 0; j < 4; ++j) acc[j] = {0.f,0.f,0.f,0.f};

    for (int kt = 0; kt < 17; ++kt) {
        const int kb = kt*64;
        const bool body = (kt < 16);

        // ---- E tile first (consumed first by premix), then V operands
        uint4 rE[8];
        #pragma unroll
        for (int g = 0; g < 8; ++g)
            rE[g] = *(const uint4*)(Eb + (size_t)g*KTE + kb + kcol0);
        long bva[2][4];
        #pragma unroll
        for (int ks = 0; ks < 2; ++ks)
            #pragma unroll
            for (int nt = 0; nt < 4; ++nt)
                bva[ks][nt] = *(const long*)(Vh + (size_t)(nt*16+lr)*KT + kb + ks*32 + lq*8);
        int4 rm[4];
        if (body) {
            #pragma unroll
            for (int j = 0; j < 4; ++j)
                rm[j] = *(const int4*)(mrow + kb + kcol0 + j*4);
        }

        // ---- premix 1 head: 16 k per thread, 2 subpasses of 8
        #pragma unroll
        for (int s = 0; s < 2; ++s) {
            const int k0 = kb + kcol0 + s*8;         // global k of 8-col group
            const bool valid = (k0 < KT);            // tail: only kc==0 survives
            f32x4 tA, tB;
            if (body) {
                const float qv = (float)q, kf0 = (float)k0;
                f32x4 dA, dB;
                dA.x = fabsf(qv-kf0);      dA.y = fabsf(qv-kf0-1.f);
                dA.z = fabsf(qv-kf0-2.f);  dA.w = fabsf(qv-kf0-3.f);
                dB.x = fabsf(qv-kf0-4.f);  dB.y = fabsf(qv-kf0-5.f);
                dB.z = fabsf(qv-kf0-6.f);  dB.w = fabsf(qv-kf0-7.f);
                tA = -dA*slmix - shf;
                tB = -dB*slmix - shf;
            } else {
                tA = {-shf,-shf,-shf,-shf};
                tB = tA;
            }
            #pragma unroll
            for (int g = 0; g < 8; ++g) {
                const uint w0 = (s == 0) ? rE[g].x : rE[g].z;
                const uint w1 = (s == 0) ? rE[g].y : rE[g].w;
                f32x2 lo0 = __builtin_amdgcn_cvt_pk_f32_fp8((int)w0, false);
                f32x2 hi0 = __builtin_amdgcn_cvt_pk_f32_fp8((int)w0, true);
                f32x2 lo1 = __builtin_amdgcn_cvt_pk_f32_fp8((int)w1, false);
                f32x2 hi1 = __builtin_amdgcn_cvt_pk_f32_fp8((int)w1, true);
                f32x4 aA; aA.x=lo0.x; aA.y=lo0.y; aA.z=hi0.x; aA.w=hi0.y;
                f32x4 aB; aB.x=lo1.x; aB.y=lo1.y; aB.z=hi1.x; aB.w=hi1.y;
                tA += aA * tw[g];
                tB += aB * tw[g];
            }
            f32x4 eA, eB;
            if (body) {
                const int4 rmA = rm[2*s], rmB = rm[2*s+1];
                eA.x = (rmA.x==0)?0.f:exp2f(tA.x);
                eA.y = (rmA.y==0)?0.f:exp2f(tA.y);
                eA.z = (rmA.z==0)?0.f:exp2f(tA.z);
                eA.w = (rmA.w==0)?0.f:exp2f(tA.w);
                eB.x = (rmB.x==0)?0.f:exp2f(tB.x);
                eB.y = (rmB.y==0)?0.f:exp2f(tB.y);
                eB.z = (rmB.z==0)?0.f:exp2f(tB.z);
                eB.w = (rmB.w==0)?0.f:exp2f(tB.w);
            } else if (valid) {          // persistent keys: no bias, no mask
                eA.x = exp2f(tA.x); eA.y = exp2f(tA.y);
                eA.z = exp2f(tA.z); eA.w = exp2f(tA.w);
                eB.x = exp2f(tB.x); eB.y = exp2f(tB.y);
                eB.z = exp2f(tB.z); eB.w = exp2f(tB.w);
            } else {
                eA = {0.f,0.f,0.f,0.f}; eB = {0.f,0.f,0.f,0.f};
            }
            sums += (eA.x+eA.y)+(eA.z+eA.w) + (eB.x+eB.y)+(eB.z+eB.w);
            int p0 = __builtin_amdgcn_cvt_pk_fp8_f32(eA.x, eA.y, 0, false);
            p0 = __builtin_amdgcn_cvt_pk_fp8_f32(eA.z, eA.w, p0, true);
            int p1 = __builtin_amdgcn_cvt_pk_fp8_f32(eB.x, eB.y, 0, false);
            p1 = __builtin_amdgcn_cvt_pk_fp8_f32(eB.z, eB.w, p1, true);
            uint2 pw; pw.x = (uint)p0; pw.y = (uint)p1;
            *(uint2*)(Psh + q_l*72 + kcol0 + s*8) = pw;
        }

        // ---- MFMA (same-wave Ps ordering via compiler lgkmcnt; no barriers)
        #pragma unroll
        for (int ks = 0; ks < 2; ++ks) {
            int ko = ks*32 + lq*8;
            long av = *(const long*)(Psh + lr*72 + ko);
            #pragma unroll
            for (int nt = 0; nt < 4; ++nt)
                acc[nt] = MFMAF8(av, bva[ks][nt], acc[nt]);
        }
    }

    // ---- row sums: reduce over the 4 kc lanes of each q_l -> 1/sum in LDS
    {
        float s = sums;
        s += __shfl_xor(s, 1); s += __shfl_xor(s, 2);
        if (kc == 0) Sred[q_l][wave] = 1.0f / s;
    }
    // (same-wave LDS write->read; compiler inserts lgkmcnt)

    // ---- normalize + store AO (bf16)
    #pragma unroll
    for (int reg = 0; reg < 4; ++reg) {
        float inv = Sred[lq*4 + reg][wave];
        int qg = ql0 + lq*4 + reg;
        #pragma unroll
        for (int nt = 0; nt < 4; ++nt) {
            int d = nt*16 + lr;
            AO[((size_t)(n*SS) + qg)*CC + h*64 + d] = f2s(acc[nt][reg] * inv);
        }
    }
}

// ---------------------------------------------------------------------------
// K5: fc (th_post folded into weights), bf16 MFMA, 64x64, XCD-swizzled.
// ---------------------------------------------------------------------------
__device__ __forceinline__ void g_load4(const short* __restrict__ src,
    size_t rowstride, int row0, int col0, int tid, short4* r)
{
    #pragma unroll
    for (int j = 0; j < 4; ++j) {
        int i = tid + j*256;
        int rr = i >> 4, cg = (i & 15)*4;
        r[j] = *(const short4*)(src + (size_t)(row0 + rr)*rowstride + col0 + cg);
    }
}
__device__ __forceinline__ void lds_store4(short* __restrict__ dst,
    int tid, const short4* r)
{
    #pragma unroll
    for (int j = 0; j < 4; ++j) {
        int i = tid + j*256;
        *(short4*)(dst + (i >> 4)*72 + (i & 15)*4) = r[j];
    }
}

__global__ __launch_bounds__(256) void fc_mfma(
    const short* __restrict__ A, const short* __restrict__ Bt,
    const float* __restrict__ bias, const float* __restrict__ x,
    short* __restrict__ out, uchar* __restrict__ out8)
{
    __shared__ short As[64*72];
    __shared__ short Bs[64*72];
    const int tid = threadIdx.x;
    const int lin = blockIdx.x + 8*blockIdx.y;      // grid (8,128)
    const int xcd = lin & 7, slot = lin >> 3;
    const int m0 = (xcd*16 + (slot & 15))*64;
    const int n0 = (slot >> 4)*64;
    const int wave = tid >> 6, lane = tid & 63;
    const int lr = lane & 15, lq = lane >> 4;

    short4 ra[4], rb[4];
    g_load4(A, CC, m0, 0, tid, ra);
    g_load4(Bt, CC, n0, 0, tid, rb);

    f32x4 acc[4];
    #pragma unroll
    for (int nt = 0; nt < 4; ++nt) acc[nt] = {0.f,0.f,0.f,0.f};

    for (int kt = 0; kt < CC; kt += 64) {
        if (kt) __syncthreads();
        lds_store4(As, tid, ra);
        lds_store4(Bs, tid, rb);
        __syncthreads();
        if (kt + 64 < CC) {
            g_load4(A, CC, m0, kt+64, tid, ra);
            g_load4(Bt, CC, n0, kt+64, tid, rb);
        }
        #pragma unroll
        for (int ks = 0; ks < 2; ++ks) {
            int ko = ks*32 + lq*8;
            short8 a = *(const short8*)(As + (wave*16 + lr)*72 + ko);
            #pragma unroll
            for (int nt = 0; nt < 4; ++nt) {
                short8 b = *(const short8*)(Bs + (nt*16 + lr)*72 + ko);
                acc[nt] = MFMA16(a, b, acc[nt]);
            }
        }
    }
    #pragma unroll
    for (int nt = 0; nt < 4; ++nt) {
        int nn = n0 + nt*16 + lr;
        #pragma unroll
        for (int reg = 0; reg < 4; ++reg) {
            int m = m0 + wave*16 + lq*4 + reg;
            float v = acc[nt][reg] + bias[nn] + x[(size_t)m*CC + nn];
            out[(size_t)m*CC + nn]  = f2s(v);
            out8[(size_t)m*CC + nn] = f2q(v);
        }
    }
}

// ---------------------------------------------------------------------------
// K6 v2: causal conv fp8 NT GEMM, BK=128 (12 K-iters), XCD-swizzled.
// ---------------------------------------------------------------------------
__device__ __forceinline__ void conv_loadA8w(const uchar* __restrict__ A,
    int m0, int kt, int tid, uint2* ra)
{
    const int shift = (kt >> 9) - 2;
    const int ci0 = kt & 511;
    #pragma unroll
    for (int j = 0; j < 4; ++j) {
        int i = tid + j*256;
        int rr = i >> 4, c8 = (i & 15)*8;
        int m = m0 + rr;
        int s = m & (SS-1);
        uint2 v = {0u, 0u};
        if (s + shift >= 0)
            v = *(const uint2*)(A + (size_t)(m + shift)*CC + ci0 + c8);
        ra[j] = v;
    }
}
__device__ __forceinline__ void g_load8w(const uchar* __restrict__ src,
    size_t rowstride, int row0, int col0, int tid, uint2* r)
{
    #pragma unroll
    for (int j = 0; j < 4; ++j) {
        int i = tid + j*256;
        int rr = i >> 4, c8 = (i & 15)*8;
        r[j] = *(const uint2*)(src + (size_t)(row0 + rr)*rowstride + col0 + c8);
    }
}
__device__ __forceinline__ void lds_store8w(uchar* __restrict__ dst,
    int tid, const uint2* r)
{
    #pragma unroll
    for (int j = 0; j < 4; ++j) {
        int i = tid + j*256;
        *(uint2*)(dst + (i >> 4)*136 + (i & 15)*8) = r[j];
    }
}

__global__ __launch_bounds__(256) void conv_mfma8(
    const uchar* __restrict__ A, const uchar* __restrict__ Bt,
    const float* __restrict__ bias, uchar* __restrict__ out8,
    short* __restrict__ out16, int f8out)
{
    __shared__ uchar As[64*136];
    __shared__ uchar Bs[64*136];
    const int tid = threadIdx.x;
    const int lin = blockIdx.x + 8*blockIdx.y;      // grid (8,128)
    const int xcd = lin & 7, slot = lin >> 3;
    const int m0 = (xcd*16 + (slot & 15))*64;
    const int n0 = (slot >> 4)*64;
    const int wave = tid >> 6, lane = tid & 63;
    const int lr = lane & 15, lq = lane >> 4;

    uint2 ra[4], rb[4];
    conv_loadA8w(A, m0, 0, tid, ra);
    g_load8w(Bt, 1536, n0, 0, tid, rb);

    f32x4 acc[4];
    #pragma unroll
    for (int nt = 0; nt < 4; ++nt) acc[nt] = {0.f,0.f,0.f,0.f};

    for (int kt = 0; kt < 1536; kt += 128) {
        if (kt) __syncthreads();
        lds_store8w(As, tid, ra);
        lds_store8w(Bs, tid, rb);
        __syncthreads();
        if (kt + 128 < 1536) {
            conv_loadA8w(A, m0, kt+128, tid, ra);
            g_load8w(Bt, 1536, n0, kt+128, tid, rb);
        }
        #pragma unroll
        for (int ks = 0; ks < 4; ++ks) {
            int ko = ks*32 + lq*8;
            long a = *(const long*)(As + (wave*16 + lr)*136 + ko);
            #pragma unroll
            for (int nt = 0; nt < 4; ++nt) {
                long b = *(const long*)(Bs + (nt*16 + lr)*136 + ko);
                acc[nt] = MFMAF8(a, b, acc[nt]);
            }
        }
    }
    #pragma unroll
    for (int nt = 0; nt < 4; ++nt) {
        int nn = n0 + nt*16 + lr;
        #pragma unroll
        for (int reg = 0; reg < 4; ++reg) {
            int m = m0 + wave*16 + lq*4 + reg;
            float v = fmaxf(acc[nt][reg]*0.0625f + bias[nn], 0.f);
            if (f8out) out8[(size_t)m*CC + nn]  = f2q(v);
            else       out16[(size_t)m*CC + nn] = f2s(v);
        }
    }
}

// ---------------------------------------------------------------------------
// K7: out = LN(relu(c2 + xres) masked) * g + b.  4 rows per block.
// ---------------------------------------------------------------------------
__global__ __launch_bounds__(256) void final_kernel(
    const short* __restrict__ c2, const short* __restrict__ xres,
    const int* __restrict__ mask, const float* __restrict__ g,
    const float* __restrict__ b, float* __restrict__ out)
{
    __shared__ float red[256];
    const int tid = threadIdx.x;
    const int m0 = blockIdx.x * 4;
    const int c0 = tid*2;
    const float2 gg = *(const float2*)(g + c0);
    const float2 bb = *(const float2*)(b + c0);

    for (int rr = 0; rr < 4; ++rr) {
        const int m = m0 + rr;
        const int n = m >> 10, s = m & 1023;
        const int mk = mask[(size_t)n*SS*SS + (size_t)s*SS];

        short2 ca = *(const short2*)(c2 + (size_t)m*CC + c0);
        short2 xa = *(const short2*)(xres + (size_t)m*CC + c0);
        float v0 = fmaxf(s2f(ca.x) + s2f(xa.x), 0.f);
        float v1 = fmaxf(s2f(ca.y) + s2f(xa.y), 0.f);
        if (mk == 0) { v0 = 0.f; v1 = 0.f; }

        red[tid] = v0 + v1;
        __syncthreads();
        for (int off = 128; off > 0; off >>= 1) {
            if (tid < off) red[tid] += red[tid + off];
            __syncthreads();
        }
        float mu = red[0] * (1.0f/512.0f);
        __syncthreads();
        float d0 = v0 - mu, d1 = v1 - mu;
        red[tid] = d0*d0 + d1*d1;
        __syncthreads();
        for (int off = 128; off > 0; off >>= 1) {
            if (tid < off) red[tid] += red[tid + off];
            __syncthreads();
        }
        float rstd = rsqrtf(red[0] * (1.0f/512.0f) + 1e-5f);
        float2 o;
        o.x = d0*rstd*gg.x + bb.x;
        o.y = d1*rstd*gg.y + bb.y;
        *(float2*)(out + (size_t)m*CC + c0) = o;
        __syncthreads();                     // red reuse next row
    }
}

// ---------------------------------------------------------------------------
extern "C" void kernel_launch(void* const* d_in, const int* in_sizes, int n_in,
                              void* d_out, int out_size, void* d_ws, size_t ws_size,
                              hipStream_t stream)
{
    const float* x      = (const float*)d_in[0];
    const int*   mask   = (const int*)  d_in[1];
    const float* Wq     = (const float*)d_in[2];
    const float* Wk     = (const float*)d_in[3];
    const float* Wv     = (const float*)d_in[4];
    const float* pk     = (const float*)d_in[5];
    const float* pv     = (const float*)d_in[6];
    const float* th_pre = (const float*)d_in[7];
    const float* th_post= (const float*)d_in[8];
    const float* fc_w   = (const float*)d_in[9];
    const float* fc_b   = (const float*)d_in[10];
    const float* c1w    = (const float*)d_in[11];
    const float* c1b    = (const float*)d_in[12];
    const float* c2w    = (const float*)d_in[13];
    const float* c2b    = (const float*)d_in[14];
    const float* lng    = (const float*)d_in[15];
    const float* lnb    = (const float*)d_in[16];
    float* out = (float*)d_out;
    (void)in_sizes; (void)n_in; (void)out_size; (void)ws_size;

    char* ws = (char*)d_ws;
    const size_t SZ_Q  = (size_t)BN*HH*SS*DD;      //  4.19 MB (fp8)
    const size_t SZ_K  = (size_t)BN*HH*KT*DD;      //  4.26 MB (fp8)
    const size_t SZ_VT = (size_t)BN*HH*DD*KT;      //  4.26 MB (fp8)
    const size_t SZ_E  = (size_t)BN*SS*HH*KTE;     // 71.3 MB (fp8, raw energy)
    const size_t SZ_A  = (size_t)BN*SS*CC*2;       //  8.39 MB (bf16)
    const size_t SZ_A8 = (size_t)BN*SS*CC;         //  4.19 MB (fp8)

    uchar* qf  = (uchar*)(ws);
    uchar* kf  = (uchar*)(ws + SZ_Q);
    uchar* vt  = (uchar*)(ws + SZ_Q + SZ_K);
    uchar* E   = (uchar*)(ws + SZ_Q + SZ_K + SZ_VT);
    short* AO  = (short*)(ws + SZ_Q + SZ_K + SZ_VT + SZ_E);
    char*  wend = ws + SZ_Q + SZ_K + SZ_VT + SZ_E + SZ_A;
    short* Bfc = (short*)(wend);
    uchar* Bc1 = (uchar*)(wend + 512*512*2);
    uchar* Bc2 = (uchar*)(wend + 512*512*2 + 512*1536);
    short* Bqkv= (short*)(wend + 512*512*2 + 2*512*1536);
    uchar* xres8 = (uchar*)(wend + 512*512*2 + 2*512*1536 + 3*64*64*2);
    short* c2buf = (short*)(wend + 512*512*2 + 2*512*1536 + 3*64*64*2 + SZ_A8);
    // Aliases (dead regions): xres(bf16) over qf+kf (dead after energy);
    // h1(fp8) over E (dead after pv_fused).
    short* xres = (short*)(ws);
    uchar* h18  = (uchar*)E;
    // total ws ~= 106 MB (ws_size >= 256 MiB)

    {
        int total = 512*512 + 2*512*1536 + 3*64*64 + BN*HH*PP*DD;
        prep_kernel<<<(total + 255)/256, 256, 0, stream>>>(
            fc_w, c1w, c2w, Wq, Wk, Wv, th_post, pk, pv,
            Bfc, Bc1, Bc2, Bqkv, kf, vt);
    }
    qkv_mfma<<<BN*SS/64*HH, 256, 0, stream>>>(x, Bqkv, qf, kf, vt);

    energy_mfma8<<<dim3(16, 64), 256, 0, stream>>>(qf, kf, E);
    pv_fused<<<dim3(8, 128), 256, 0, stream>>>(E, vt, mask, th_pre, AO);

    fc_mfma<<<dim3(8, 128), 256, 0, stream>>>(AO, Bfc, fc_b, x, xres, xres8);
    conv_mfma8<<<dim3(8, 128), 256, 0, stream>>>(xres8, Bc1, c1b, h18, (short*)nullptr, 1);
    conv_mfma8<<<dim3(8, 128), 256, 0, stream>>>(h18, Bc2, c2b, (uchar*)nullptr, c2buf, 0);
    final_kernel<<<BN*SS/4, 256, 0, stream>>>(c2buf, xres, mask, lng, lnb, out);
}

// Round 8
// 296.454 us; speedup vs baseline: 1.1187x; 1.0096x over previous
//
#include <hip/hip_runtime.h>
#include <hip/hip_bf16.h>

#define BN 8
#define SS 1024
#define CC 512
#define HH 8
#define DD 64
#define PP 16
#define KT 1040
#define KTE 1088   // E head-row stride, padded to 64B multiple

typedef __hip_bfloat16 bf16;
typedef unsigned char uchar;
typedef unsigned short ushort;
typedef unsigned int uint;
typedef __attribute__((ext_vector_type(8))) short short8;
typedef __attribute__((ext_vector_type(4))) float f32x4;
typedef __attribute__((ext_vector_type(2))) float f32x2;

__device__ __forceinline__ short f2s(float v){ bf16 b = __float2bfloat16(v); return *(short*)&b; }
__device__ __forceinline__ float s2f(short s){ bf16 b; *(short*)&b = s; return __bfloat162float(b); }
__device__ __forceinline__ uchar f2q(float v){          // f32 -> fp8 e4m3 byte
    return (uchar)__builtin_amdgcn_cvt_pk_fp8_f32(v, v, 0, false);
}
__device__ __forceinline__ float rfl(float x){          // force to SGPR
    return __int_as_float(__builtin_amdgcn_readfirstlane(__float_as_int(x)));
}

#define MFMA16(a,b,c)  __builtin_amdgcn_mfma_f32_16x16x32_bf16(a,b,c,0,0,0)
#define MFMAF8(a,b,c)  __builtin_amdgcn_mfma_f32_16x16x32_fp8_fp8(a,b,c,0,0,0)

// ---------------------------------------------------------------------------
// P0: weight pre-conversion + persistent-token tails + mask bit-packing.
// pm[n][q] = 1024-bit mask row (32 uints): bit (k&31) of word (k>>5) =
// mask[n][q][k] != 0.  1 MB total; lets pv test 16 keys with one uint.
// ---------------------------------------------------------------------------
__global__ __launch_bounds__(256) void prep_kernel(
    const float* __restrict__ fc_w, const float* __restrict__ c1w,
    const float* __restrict__ c2w, const float* __restrict__ Wq,
    const float* __restrict__ Wk, const float* __restrict__ Wv,
    const float* __restrict__ th_post,
    const float* __restrict__ pk, const float* __restrict__ pv,
    const int* __restrict__ mask,
    short* __restrict__ Bfc, uchar* __restrict__ Bc1,
    uchar* __restrict__ Bc2, short* __restrict__ Bqkv,
    uchar* __restrict__ kf, uchar* __restrict__ vt,
    uint* __restrict__ pm)
{
    int i = blockIdx.x*256 + threadIdx.x;
    const int NFC = 512*512, NCV = 512*1536, NQ = 3*64*64, NP = BN*HH*PP*DD;
    const int NM = BN*SS*32;
    if (i < NFC) {
        int c = i >> 9, r = i & 511;
        int g = r >> 6, d = r & 63;
        float s = 0.f;
        #pragma unroll
        for (int h = 0; h < 8; ++h)
            s += fc_w[(size_t)c*512 + h*64 + d] * th_post[h*8 + g];
        Bfc[i] = f2s(s);
        return;
    }
    i -= NFC;
    if (i < NCV) {
        int o = i/1536, r = i%1536, dk = r>>9, ci = r&511;
        Bc1[i] = f2q(c1w[(o*512+ci)*3+dk] * 16.f); return;
    }
    i -= NCV;
    if (i < NCV) {
        int o = i/1536, r = i%1536, dk = r>>9, ci = r&511;
        Bc2[i] = f2q(c2w[(o*512+ci)*3+dk] * 16.f); return;
    }
    i -= NCV;
    if (i < NQ) {
        int w = i >> 12, rest = i & 4095;
        const float* W = (w==0)?Wq:(w==1)?Wk:Wv;
        Bqkv[i] = f2s(W[((rest>>6)&63)*64 + (rest&63)]);
        return;
    }
    i -= NQ;
    if (i < NP) {
        int d = i & 63, p = (i >> 6) & 15, h = (i >> 10) & 7, n = i >> 13;
        size_t src = ((size_t)p*HH + h)*DD + d;
        kf[(((size_t)(n*HH+h))*KT + SS + p)*DD + d] = f2q(pk[src]);
        vt[(((size_t)(n*HH+h))*DD + d)*KT + SS + p] = f2q(pv[src]);
        return;
    }
    i -= NP;
    if (i < NM) {
        int w = i & 31, q = (i >> 5) & 1023, n = i >> 15;
        const int* mr = mask + ((size_t)n*SS + q)*SS + w*32;
        uint bits = 0;
        #pragma unroll
        for (int j = 0; j < 8; ++j) {
            int4 m = *(const int4*)(mr + j*4);
            bits |= (m.x != 0 ? 1u : 0u) << (j*4 + 0);
            bits |= (m.y != 0 ? 1u : 0u) << (j*4 + 1);
            bits |= (m.z != 0 ? 1u : 0u) << (j*4 + 2);
            bits |= (m.w != 0 ? 1u : 0u) << (j*4 + 3);
        }
        pm[(size_t)(n*SS + q)*32 + w] = bits;
    }
}

// ---------------------------------------------------------------------------
// K1 v2: QKV projection, bf16 MFMA, XCD-swizzled.
// q/k out fp8 [s][d]; V -> transposed fp8 vt[nh][d][k=s].
// ---------------------------------------------------------------------------
__global__ __launch_bounds__(256) void qkv_mfma(
    const float* __restrict__ x, const short* __restrict__ Bqkv,
    uchar* __restrict__ qf, uchar* __restrict__ kf, uchar* __restrict__ vt)
{
    __shared__ short Xs[64*72];
    __shared__ short Ws[192*72];
    const int tid = threadIdx.x;
    const int lin = blockIdx.x;                     // grid 1024 linear
    const int xcd = lin & 7, slot = lin >> 3;       // slot in [0,128)
    const int m0 = (xcd*16 + (slot & 15))*64;
    const int h = slot >> 4;
    const int wave = tid >> 6, lane = tid & 63;
    const int lr = lane & 15, lq = lane >> 4;

    for (int i = tid; i < 1024; i += 256) {
        int r = i >> 4, cg = (i & 15)*4;
        float4 v = *(const float4*)(x + (size_t)(m0+r)*CC + h*64 + cg);
        Xs[r*72+cg+0] = f2s(v.x); Xs[r*72+cg+1] = f2s(v.y);
        Xs[r*72+cg+2] = f2s(v.z); Xs[r*72+cg+3] = f2s(v.w);
    }
    for (int i = tid; i < 3072; i += 256) {
        int r = i >> 4, cg = (i & 15)*4;
        *(short4*)(Ws + r*72 + cg) = *(const short4*)(Bqkv + (size_t)r*64 + cg);
    }
    __syncthreads();

    f32x4 acc[12];
    #pragma unroll
    for (int nt = 0; nt < 12; ++nt) acc[nt] = {0.f,0.f,0.f,0.f};
    #pragma unroll
    for (int ks = 0; ks < 2; ++ks) {
        int ko = ks*32 + lq*8;
        short8 a = *(const short8*)(Xs + (wave*16 + lr)*72 + ko);
        #pragma unroll
        for (int nt = 0; nt < 12; ++nt) {
            short8 b = *(const short8*)(Ws + (nt*16 + lr)*72 + ko);
            acc[nt] = MFMA16(a, b, acc[nt]);
        }
    }
    #pragma unroll
    for (int nt = 0; nt < 12; ++nt) {
        int ep = nt*16 + lr;
        int w = ep >> 6, e = ep & 63;
        #pragma unroll
        for (int reg = 0; reg < 4; ++reg) {
            int m = m0 + wave*16 + lq*4 + reg;
            int n = m >> 10, s = m & 1023;
            float v = acc[nt][reg];
            if (w == 0)      qf[((size_t)(n*HH+h)*SS + s)*DD + e] = f2q(v);
            else if (w == 1) kf[((size_t)(n*HH+h)*KT + s)*DD + e] = f2q(v);
            else             vt[(((size_t)(n*HH+h))*DD + e)*KT + s] = f2q(v);
        }
    }
}

// ---------------------------------------------------------------------------
// K2 v3: energy (RAW, pre-mix), fp8 MFMA NT, XCD-swizzled.
// E layout: [n][q][h][KTE] with KTE=1088 (64B-aligned head rows).
// ---------------------------------------------------------------------------
__device__ __forceinline__ void en_loadK(const uchar* __restrict__ kf,
    int nh, int kt, int tid, uint2* rk)
{
    #pragma unroll
    for (int j = 0; j < 2; ++j) {
        int i = tid + j*256;
        int r = i >> 3, c8 = (i & 7)*8;
        int kcol = kt*64 + r;
        uint2 v = {0u, 0u};
        if (kcol < KT)
            v = *(const uint2*)(kf + ((size_t)nh*KT + kcol)*DD + c8);
        rk[j] = v;
    }
}

__global__ __launch_bounds__(256) void energy_mfma8(
    const uchar* __restrict__ qf, const uchar* __restrict__ kf,
    uchar* __restrict__ E)
{
    __shared__ uchar Qs[64*72];
    __shared__ uchar Ks[64*72];
    const int tid = threadIdx.x;
    const int lin = blockIdx.x + 16*blockIdx.y;     // grid (16, 64)
    const int xcd = lin & 7, slot = lin >> 3;       // slot in [0,128)
    const int nh = xcd*8 + (slot & 7);
    const int mt = slot >> 3;
    const int wave = tid >> 6, lane = tid & 63;
    const int lr = lane & 15, lq = lane >> 4;
    const int n = nh >> 3, h = nh & 7;

    #pragma unroll
    for (int j = 0; j < 2; ++j) {
        int i = tid + j*256;
        int r = i >> 3, c8 = (i & 7)*8;
        *(uint2*)(Qs + r*72 + c8) =
            *(const uint2*)(qf + ((size_t)nh*SS + mt*64 + r)*DD + c8);
    }

    uint2 rk[2];
    en_loadK(kf, nh, 0, tid, rk);

    for (int kt = 0; kt < 17; ++kt) {
        if (kt) __syncthreads();
        #pragma unroll
        for (int j = 0; j < 2; ++j) {
            int i = tid + j*256;
            *(uint2*)(Ks + (i >> 3)*72 + (i & 7)*8) = rk[j];
        }
        __syncthreads();
        if (kt + 1 < 17) en_loadK(kf, nh, kt+1, tid, rk);

        f32x4 acc[4];
        #pragma unroll
        for (int nt = 0; nt < 4; ++nt) acc[nt] = {0.f,0.f,0.f,0.f};
        #pragma unroll
        for (int ks = 0; ks < 2; ++ks) {
            int ko = ks*32 + lq*8;
            long a = *(const long*)(Qs + (wave*16 + lr)*72 + ko);
            #pragma unroll
            for (int nt = 0; nt < 4; ++nt) {
                long b = *(const long*)(Ks + (nt*16 + lr)*72 + ko);
                acc[nt] = MFMAF8(a, b, acc[nt]);
            }
        }
        #pragma unroll
        for (int nt = 0; nt < 4; ++nt) {
            int kcol = kt*64 + nt*16 + lr;
            if (kcol >= KT) continue;
            #pragma unroll
            for (int reg = 0; reg < 4; ++reg) {
                int q = mt*64 + wave*16 + lq*4 + reg;
                E[(((size_t)(n*SS + q))*HH + h)*KTE + kcol] = f2q(acc[nt][reg]);
            }
        }
    }
}

// ---------------------------------------------------------------------------
// K3+K4 fused: pv_fused v7 = v6 (1 head/wave, grid(8,128), lb(256,2)) +
// E register double-buffer + bit-packed mask.
// v6 was spill-free (80 VGPR) but kept ~500cyc E latency exposed per tile
// (inline load->use). v7 prefetches tile kt+1's E (8xuint4, +32 VGPR) at the
// top of iter kt, and replaces the 4x int4 mask loads (16 VGPR) with ONE
// uint from the prep-built bitmask pm. Peak live ~120 VGPR < 128 -> no
// spill AND latency hidden. Barrier-free; waves fully independent.
// ---------------------------------------------------------------------------
__global__ __launch_bounds__(256, 2) void pv_fused(
    const uchar* __restrict__ E, const uchar* __restrict__ vt,
    const uint* __restrict__ pm, const float* __restrict__ th_pre,
    short* __restrict__ AO)
{
    __shared__ uchar Ps[4*16*72];        // 4.5 KB: p fp8, [wave][q16][72]
    __shared__ float Sred[16][4];        // 1/rowsum per (q, wave)
    const int tid  = threadIdx.x;
    const int n    = blockIdx.x;         // 8  (== XCD)
    const int yy   = blockIdx.y;         // 128 = 64 q-tiles x 2 head-groups
    const int ql0  = (yy >> 1) * 16;
    const int hg   = (yy & 1) * 4;
    const int wave = tid >> 6, lane = tid & 63;
    const int h    = hg + wave;          // this wave's head
    const int lr = lane & 15, lq = lane >> 4;   // MFMA decomposition
    const int q_l = lane >> 2, kc = lane & 3;   // premix decomposition
    const int q  = ql0 + q_l;
    const int kcol0 = kc*16;             // this thread's 16-k group in a tile
    const int mshift = (kc & 1)*16;      // bit offset of the stripe in pm word

    // this head's talking-heads weights (8 SGPRs) + mixed slope
    const float sc = 0.044194173824159216f * 1.4426950408889634f; // 1/sqrt(C)*log2e
    float tw[8], slmix, shf;
    {
        const float slv[8] = {0.5f,0.25f,0.125f,0.0625f,
                              0.03125f,0.015625f,0.0078125f,0.00390625f};
        const float maxd = (float)((q > SS-1-q) ? q : (SS-1-q));
        float sm = 0.f;
        #pragma unroll
        for (int g = 0; g < 8; ++g) {
            float v = rfl(th_pre[h*8+g] * sc);
            tw[g] = v;
            sm += v * slv[g];
        }
        slmix = rfl(sm);
        shf = fmaxf(0.f, -slmix * maxd);          // per-thread (q) VGPR
    }

    const uchar* Eb  = E  + ((size_t)(n*SS + q))*HH*KTE;  // head-0 row, this q
    const uchar* Vh  = vt + ((size_t)(n*HH) + h)*DD*KT;
    const uint* pmrow = pm + (size_t)(n*SS + q)*32;
    uchar* Psh = Ps + wave*1152;

    // ---- prologue: tile-0 E + mask word
    uint4 rE[8];
    #pragma unroll
    for (int g = 0; g < 8; ++g)
        rE[g] = *(const uint4*)(Eb + (size_t)g*KTE + kcol0);
    uint pmw = pmrow[(kc >> 1)];

    float sums = 0.f;
    f32x4 acc[4];
    #pragma unroll
    for (int j = 0; j < 4; ++j) acc[j] = {0.f,0.f,0.f,0.f};

    for (int kt = 0; kt < 17; ++kt) {
        const int kb = kt*64;
        const bool body = (kt < 16);

        // ---- V operands for this tile (L2-resident; overlap premix)
        long bva[2][4];
        #pragma unroll
        for (int ks = 0; ks < 2; ++ks)
            #pragma unroll
            for (int nt = 0; nt < 4; ++nt)
                bva[ks][nt] = *(const long*)(Vh + (size_t)(nt*16+lr)*KT + kb + ks*32 + lq*8);

        // ---- prefetch NEXT tile's E + mask word (hidden under premix+MFMA)
        uint4 nE[8]; uint npmw = 0;
        if (kt < 16) {
            const int nb = kb + 64 + kcol0;
            #pragma unroll
            for (int g = 0; g < 8; ++g)
                nE[g] = *(const uint4*)(Eb + (size_t)g*KTE + nb);
            if (kt + 1 < 16) npmw = pmrow[(kt+1)*2 + (kc >> 1)];
        }

        // ---- premix 1 head: 16 k per thread, 2 subpasses of 8
        #pragma unroll
        for (int s = 0; s < 2; ++s) {
            const int k0 = kb + kcol0 + s*8;         // global k of 8-col group
            const bool valid = (k0 < KT);            // tail: only kc==0 survives
            f32x4 tA, tB;
            if (body) {
                const float qv = (float)q, kf0 = (float)k0;
                f32x4 dA, dB;
                dA.x = fabsf(qv-kf0);      dA.y = fabsf(qv-kf0-1.f);
                dA.z = fabsf(qv-kf0-2.f);  dA.w = fabsf(qv-kf0-3.f);
                dB.x = fabsf(qv-kf0-4.f);  dB.y = fabsf(qv-kf0-5.f);
                dB.z = fabsf(qv-kf0-6.f);  dB.w = fabsf(qv-kf0-7.f);
                tA = -dA*slmix - shf;
                tB = -dB*slmix - shf;
            } else {
                tA = {-shf,-shf,-shf,-shf};
                tB = tA;
            }
            #pragma unroll
            for (int g = 0; g < 8; ++g) {
                const uint w0 = (s == 0) ? rE[g].x : rE[g].z;
                const uint w1 = (s == 0) ? rE[g].y : rE[g].w;
                f32x2 lo0 = __builtin_amdgcn_cvt_pk_f32_fp8((int)w0, false);
                f32x2 hi0 = __builtin_amdgcn_cvt_pk_f32_fp8((int)w0, true);
                f32x2 lo1 = __builtin_amdgcn_cvt_pk_f32_fp8((int)w1, false);
                f32x2 hi1 = __builtin_amdgcn_cvt_pk_f32_fp8((int)w1, true);
                f32x4 aA; aA.x=lo0.x; aA.y=lo0.y; aA.z=hi0.x; aA.w=hi0.y;
                f32x4 aB; aB.x=lo1.x; aB.y=lo1.y; aB.z=hi1.x; aB.w=hi1.y;
                tA += aA * tw[g];
                tB += aB * tw[g];
            }
            f32x4 eA, eB;
            if (body) {
                const uint bits = (pmw >> (mshift + s*8)) & 0xffu;
                eA.x = (bits & 0x01u) ? exp2f(tA.x) : 0.f;
                eA.y = (bits & 0x02u) ? exp2f(tA.y) : 0.f;
                eA.z = (bits & 0x04u) ? exp2f(tA.z) : 0.f;
                eA.w = (bits & 0x08u) ? exp2f(tA.w) : 0.f;
                eB.x = (bits & 0x10u) ? exp2f(tB.x) : 0.f;
                eB.y = (bits & 0x20u) ? exp2f(tB.y) : 0.f;
                eB.z = (bits & 0x40u) ? exp2f(tB.z) : 0.f;
                eB.w = (bits & 0x80u) ? exp2f(tB.w) : 0.f;
            } else if (valid) {          // persistent keys: no bias, no mask
                eA.x = exp2f(tA.x); eA.y = exp2f(tA.y);
                eA.z = exp2f(tA.z); eA.w = exp2f(tA.w);
                eB.x = exp2f(tB.x); eB.y = exp2f(tB.y);
                eB.z = exp2f(tB.z); eB.w = exp2f(tB.w);
            } else {
                eA = {0.f,0.f,0.f,0.f}; eB = {0.f,0.f,0.f,0.f};
            }
            sums += (eA.x+eA.y)+(eA.z+eA.w) + (eB.x+eB.y)+(eB.z+eB.w);
            int p0 = __builtin_amdgcn_cvt_pk_fp8_f32(eA.x, eA.y, 0, false);
            p0 = __builtin_amdgcn_cvt_pk_fp8_f32(eA.z, eA.w, p0, true);
            int p1 = __builtin_amdgcn_cvt_pk_fp8_f32(eB.x, eB.y, 0, false);
            p1 = __builtin_amdgcn_cvt_pk_fp8_f32(eB.z, eB.w, p1, true);
            uint2 pw; pw.x = (uint)p0; pw.y = (uint)p1;
            *(uint2*)(Psh + q_l*72 + kcol0 + s*8) = pw;
        }

        // ---- MFMA (same-wave Ps ordering via compiler lgkmcnt; no barriers)
        #pragma unroll
        for (int ks = 0; ks < 2; ++ks) {
            int ko = ks*32 + lq*8;
            long av = *(const long*)(Psh + lr*72 + ko);
            #pragma unroll
            for (int nt = 0; nt < 4; ++nt)
                acc[nt] = MFMAF8(av, bva[ks][nt], acc[nt]);
        }

        // ---- rotate double buffers (static indices only)
        if (kt < 16) {
            #pragma unroll
            for (int g = 0; g < 8; ++g) rE[g] = nE[g];
            pmw = npmw;
        }
    }

    // ---- row sums: reduce over the 4 kc lanes of each q_l -> 1/sum in LDS
    {
        float s = sums;
        s += __shfl_xor(s, 1); s += __shfl_xor(s, 2);
        if (kc == 0) Sred[q_l][wave] = 1.0f / s;
    }
    // (same-wave LDS write->read; compiler inserts lgkmcnt)

    // ---- normalize + store AO (bf16)
    #pragma unroll
    for (int reg = 0; reg < 4; ++reg) {
        float inv = Sred[lq*4 + reg][wave];
        int qg = ql0 + lq*4 + reg;
        #pragma unroll
        for (int nt = 0; nt < 4; ++nt) {
            int d = nt*16 + lr;
            AO[((size_t)(n*SS) + qg)*CC + h*64 + d] = f2s(acc[nt][reg] * inv);
        }
    }
}

// ---------------------------------------------------------------------------
// K5: fc (th_post folded into weights), bf16 MFMA, 64x64, XCD-swizzled.
// ---------------------------------------------------------------------------
__device__ __forceinline__ void g_load4(const short* __restrict__ src,
    size_t rowstride, int row0, int col0, int tid, short4* r)
{
    #pragma unroll
    for (int j = 0; j < 4; ++j) {
        int i = tid + j*256;
        int rr = i >> 4, cg = (i & 15)*4;
        r[j] = *(const short4*)(src + (size_t)(row0 + rr)*rowstride + col0 + cg);
    }
}
__device__ __forceinline__ void lds_store4(short* __restrict__ dst,
    int tid, const short4* r)
{
    #pragma unroll
    for (int j = 0; j < 4; ++j) {
        int i = tid + j*256;
        *(short4*)(dst + (i >> 4)*72 + (i & 15)*4) = r[j];
    }
}

__global__ __launch_bounds__(256) void fc_mfma(
    const short* __restrict__ A, const short* __restrict__ Bt,
    const float* __restrict__ bias, const float* __restrict__ x,
    short* __restrict__ out, uchar* __restrict__ out8)
{
    __shared__ short As[64*72];
    __shared__ short Bs[64*72];
    const int tid = threadIdx.x;
    const int lin = blockIdx.x + 8*blockIdx.y;      // grid (8,128)
    const int xcd = lin & 7, slot = lin >> 3;
    const int m0 = (xcd*16 + (slot & 15))*64;
    const int n0 = (slot >> 4)*64;
    const int wave = tid >> 6, lane = tid & 63;
    const int lr = lane & 15, lq = lane >> 4;

    short4 ra[4], rb[4];
    g_load4(A, CC, m0, 0, tid, ra);
    g_load4(Bt, CC, n0, 0, tid, rb);

    f32x4 acc[4];
    #pragma unroll
    for (int nt = 0; nt < 4; ++nt) acc[nt] = {0.f,0.f,0.f,0.f};

    for (int kt = 0; kt < CC; kt += 64) {
        if (kt) __syncthreads();
        lds_store4(As, tid, ra);
        lds_store4(Bs, tid, rb);
        __syncthreads();
        if (kt + 64 < CC) {
            g_load4(A, CC, m0, kt+64, tid, ra);
            g_load4(Bt, CC, n0, kt+64, tid, rb);
        }
        #pragma unroll
        for (int ks = 0; ks < 2; ++ks) {
            int ko = ks*32 + lq*8;
            short8 a = *(const short8*)(As + (wave*16 + lr)*72 + ko);
            #pragma unroll
            for (int nt = 0; nt < 4; ++nt) {
                short8 b = *(const short8*)(Bs + (nt*16 + lr)*72 + ko);
                acc[nt] = MFMA16(a, b, acc[nt]);
            }
        }
    }
    #pragma unroll
    for (int nt = 0; nt < 4; ++nt) {
        int nn = n0 + nt*16 + lr;
        #pragma unroll
        for (int reg = 0; reg < 4; ++reg) {
            int m = m0 + wave*16 + lq*4 + reg;
            float v = acc[nt][reg] + bias[nn] + x[(size_t)m*CC + nn];
            out[(size_t)m*CC + nn]  = f2s(v);
            out8[(size_t)m*CC + nn] = f2q(v);
        }
    }
}

// ---------------------------------------------------------------------------
// K6 v2: causal conv fp8 NT GEMM, BK=128 (12 K-iters), XCD-swizzled.
// ---------------------------------------------------------------------------
__device__ __forceinline__ void conv_loadA8w(const uchar* __restrict__ A,
    int m0, int kt, int tid, uint2* ra)
{
    const int shift = (kt >> 9) - 2;
    const int ci0 = kt & 511;
    #pragma unroll
    for (int j = 0; j < 4; ++j) {
        int i = tid + j*256;
        int rr = i >> 4, c8 = (i & 15)*8;
        int m = m0 + rr;
        int s = m & (SS-1);
        uint2 v = {0u, 0u};
        if (s + shift >= 0)
            v = *(const uint2*)(A + (size_t)(m + shift)*CC + ci0 + c8);
        ra[j] = v;
    }
}
__device__ __forceinline__ void g_load8w(const uchar* __restrict__ src,
    size_t rowstride, int row0, int col0, int tid, uint2* r)
{
    #pragma unroll
    for (int j = 0; j < 4; ++j) {
        int i = tid + j*256;
        int rr = i >> 4, c8 = (i & 15)*8;
        r[j] = *(const uint2*)(src + (size_t)(row0 + rr)*rowstride + col0 + c8);
    }
}
__device__ __forceinline__ void lds_store8w(uchar* __restrict__ dst,
    int tid, const uint2* r)
{
    #pragma unroll
    for (int j = 0; j < 4; ++j) {
        int i = tid + j*256;
        *(uint2*)(dst + (i >> 4)*136 + (i & 15)*8) = r[j];
    }
}

__global__ __launch_bounds__(256) void conv_mfma8(
    const uchar* __restrict__ A, const uchar* __restrict__ Bt,
    const float* __restrict__ bias, uchar* __restrict__ out8,
    short* __restrict__ out16, int f8out)
{
    __shared__ uchar As[64*136];
    __shared__ uchar Bs[64*136];
    const int tid = threadIdx.x;
    const int lin = blockIdx.x + 8*blockIdx.y;      // grid (8,128)
    const int xcd = lin & 7, slot = lin >> 3;
    const int m0 = (xcd*16 + (slot & 15))*64;
    const int n0 = (slot >> 4)*64;
    const int wave = tid >> 6, lane = tid & 63;
    const int lr = lane & 15, lq = lane >> 4;

    uint2 ra[4], rb[4];
    conv_loadA8w(A, m0, 0, tid, ra);
    g_load8w(Bt, 1536, n0, 0, tid, rb);

    f32x4 acc[4];
    #pragma unroll
    for (int nt = 0; nt < 4; ++nt) acc[nt] = {0.f,0.f,0.f,0.f};

    for (int kt = 0; kt < 1536; kt += 128) {
        if (kt) __syncthreads();
        lds_store8w(As, tid, ra);
        lds_store8w(Bs, tid, rb);
        __syncthreads();
        if (kt + 128 < 1536) {
            conv_loadA8w(A, m0, kt+128, tid, ra);
            g_load8w(Bt, 1536, n0, kt+128, tid, rb);
        }
        #pragma unroll
        for (int ks = 0; ks < 4; ++ks) {
            int ko = ks*32 + lq*8;
            long a = *(const long*)(As + (wave*16 + lr)*136 + ko);
            #pragma unroll
            for (int nt = 0; nt < 4; ++nt) {
                long b = *(const long*)(Bs + (nt*16 + lr)*136 + ko);
                acc[nt] = MFMAF8(a, b, acc[nt]);
            }
        }
    }
    #pragma unroll
    for (int nt = 0; nt < 4; ++nt) {
        int nn = n0 + nt*16 + lr;
        #pragma unroll
        for (int reg = 0; reg < 4; ++reg) {
            int m = m0 + wave*16 + lq*4 + reg;
            float v = fmaxf(acc[nt][reg]*0.0625f + bias[nn], 0.f);
            if (f8out) out8[(size_t)m*CC + nn]  = f2q(v);
            else       out16[(size_t)m*CC + nn] = f2s(v);
        }
    }
}

// ---------------------------------------------------------------------------
// K7: out = LN(relu(c2 + xres) masked) * g + b.  4 rows per block.
// ---------------------------------------------------------------------------
__global__ __launch_bounds__(256) void final_kernel(
    const short* __restrict__ c2, const short* __restrict__ xres,
    const int* __restrict__ mask, const float* __restrict__ g,
    const float* __restrict__ b, float* __restrict__ out)
{
    __shared__ float red[256];
    const int tid = threadIdx.x;
    const int m0 = blockIdx.x * 4;
    const int c0 = tid*2;
    const float2 gg = *(const float2*)(g + c0);
    const float2 bb = *(const float2*)(b + c0);

    for (int rr = 0; rr < 4; ++rr) {
        const int m = m0 + rr;
        const int n = m >> 10, s = m & 1023;
        const int mk = mask[(size_t)n*SS*SS + (size_t)s*SS];

        short2 ca = *(const short2*)(c2 + (size_t)m*CC + c0);
        short2 xa = *(const short2*)(xres + (size_t)m*CC + c0);
        float v0 = fmaxf(s2f(ca.x) + s2f(xa.x), 0.f);
        float v1 = fmaxf(s2f(ca.y) + s2f(xa.y), 0.f);
        if (mk == 0) { v0 = 0.f; v1 = 0.f; }

        red[tid] = v0 + v1;
        __syncthreads();
        for (int off = 128; off > 0; off >>= 1) {
            if (tid < off) red[tid] += red[tid + off];
            __syncthreads();
        }
        float mu = red[0] * (1.0f/512.0f);
        __syncthreads();
        float d0 = v0 - mu, d1 = v1 - mu;
        red[tid] = d0*d0 + d1*d1;
        __syncthreads();
        for (int off = 128; off > 0; off >>= 1) {
            if (tid < off) red[tid] += red[tid + off];
            __syncthreads();
        }
        float rstd = rsqrtf(red[0] * (1.0f/512.0f) + 1e-5f);
        float2 o;
        o.x = d0*rstd*gg.x + bb.x;
        o.y = d1*rstd*gg.y + bb.y;
        *(float2*)(out + (size_t)m*CC + c0) = o;
        __syncthreads();                     // red reuse next row
    }
}

// ---------------------------------------------------------------------------
extern "C" void kernel_launch(void* const* d_in, const int* in_sizes, int n_in,
                              void* d_out, int out_size, void* d_ws, size_t ws_size,
                              hipStream_t stream)
{
    const float* x      = (const float*)d_in[0];
    const int*   mask   = (const int*)  d_in[1];
    const float* Wq     = (const float*)d_in[2];
    const float* Wk     = (const float*)d_in[3];
    const float* Wv     = (const float*)d_in[4];
    const float* pk     = (const float*)d_in[5];
    const float* pv     = (const float*)d_in[6];
    const float* th_pre = (const float*)d_in[7];
    const float* th_post= (const float*)d_in[8];
    const float* fc_w   = (const float*)d_in[9];
    const float* fc_b   = (const float*)d_in[10];
    const float* c1w    = (const float*)d_in[11];
    const float* c1b    = (const float*)d_in[12];
    const float* c2w    = (const float*)d_in[13];
    const float* c2b    = (const float*)d_in[14];
    const float* lng    = (const float*)d_in[15];
    const float* lnb    = (const float*)d_in[16];
    float* out = (float*)d_out;
    (void)in_sizes; (void)n_in; (void)out_size; (void)ws_size;

    char* ws = (char*)d_ws;
    const size_t SZ_Q  = (size_t)BN*HH*SS*DD;      //  4.19 MB (fp8)
    const size_t SZ_K  = (size_t)BN*HH*KT*DD;      //  4.26 MB (fp8)
    const size_t SZ_VT = (size_t)BN*HH*DD*KT;      //  4.26 MB (fp8)
    const size_t SZ_E  = (size_t)BN*SS*HH*KTE;     // 71.3 MB (fp8, raw energy)
    const size_t SZ_A  = (size_t)BN*SS*CC*2;       //  8.39 MB (bf16)
    const size_t SZ_A8 = (size_t)BN*SS*CC;         //  4.19 MB (fp8)

    uchar* qf  = (uchar*)(ws);
    uchar* kf  = (uchar*)(ws + SZ_Q);
    uchar* vt  = (uchar*)(ws + SZ_Q + SZ_K);
    uchar* E   = (uchar*)(ws + SZ_Q + SZ_K + SZ_VT);
    short* AO  = (short*)(ws + SZ_Q + SZ_K + SZ_VT + SZ_E);
    char*  wend = ws + SZ_Q + SZ_K + SZ_VT + SZ_E + SZ_A;
    short* Bfc = (short*)(wend);
    uchar* Bc1 = (uchar*)(wend + 512*512*2);
    uchar* Bc2 = (uchar*)(wend + 512*512*2 + 512*1536);
    short* Bqkv= (short*)(wend + 512*512*2 + 2*512*1536);
    uchar* xres8 = (uchar*)(wend + 512*512*2 + 2*512*1536 + 3*64*64*2);
    short* c2buf = (short*)(wend + 512*512*2 + 2*512*1536 + 3*64*64*2 + SZ_A8);
    uint*  pmb   = (uint*) (wend + 512*512*2 + 2*512*1536 + 3*64*64*2 + SZ_A8 + SZ_A);
    // Aliases (dead regions): xres(bf16) over qf+kf (dead after energy);
    // h1(fp8) over E (dead after pv_fused).
    short* xres = (short*)(ws);
    uchar* h18  = (uchar*)E;
    // total ws ~= 108 MB (ws_size >= 256 MiB)

    {
        int total = 512*512 + 2*512*1536 + 3*64*64 + BN*HH*PP*DD + BN*SS*32;
        prep_kernel<<<(total + 255)/256, 256, 0, stream>>>(
            fc_w, c1w, c2w, Wq, Wk, Wv, th_post, pk, pv, mask,
            Bfc, Bc1, Bc2, Bqkv, kf, vt, pmb);
    }
    qkv_mfma<<<BN*SS/64*HH, 256, 0, stream>>>(x, Bqkv, qf, kf, vt);

    energy_mfma8<<<dim3(16, 64), 256, 0, stream>>>(qf, kf, E);
    pv_fused<<<dim3(8, 128), 256, 0, stream>>>(E, vt, pmb, th_pre, AO);

    fc_mfma<<<dim3(8, 128), 256, 0, stream>>>(AO, Bfc, fc_b, x, xres, xres8);
    conv_mfma8<<<dim3(8, 128), 256, 0, stream>>>(xres8, Bc1, c1b, h18, (short*)nullptr, 1);
    conv_mfma8<<<dim3(8, 128), 256, 0, stream>>>(h18, Bc2, c2b, (uchar*)nullptr, c2buf, 0);
    final_kernel<<<BN*SS/4, 256, 0, stream>>>(c2buf, xres, mask, lng, lnb, out);
}